// Round 4
// baseline (229.904 us; speedup 1.0000x reference)
//
#include <hip/hip_runtime.h>
#include <math.h>
#include <stdint.h>

#define B_    2
#define T_    2048
#define C_    2048
#define NH_   16
#define G_    4
#define HS_   128
#define WIN_  512
#define NQKV_ 3072
#define M_    4096
#define SCALE_ 0.08838834764831845f

typedef __attribute__((ext_vector_type(8))) __bf16 bf16x8;
typedef __attribute__((ext_vector_type(4))) float f32x4;
typedef unsigned short u16;

static __device__ __forceinline__ u16 f2bf(float f) {
  union { float f; unsigned u; } v; v.f = f;
  unsigned r = v.u + 0x7fffu + ((v.u >> 16) & 1u);
  return (u16)(r >> 16);
}
static __device__ __forceinline__ float bf2f(u16 h) {
  union { unsigned u; float f; } v; v.u = ((unsigned)h) << 16; return v.f;
}
static __device__ __forceinline__ bf16x8 ldg8(const u16* p) {
  return *(const bf16x8*)(const void*)p;
}

// ---------------- x fp32 -> bf16 ----------------
__global__ void cvt_bf16(const float* __restrict__ in, u16* __restrict__ out) {
  int i = blockIdx.x * 256 + threadIdx.x;
  float4 v = ((const float4*)in)[i];
  ushort4 o;
  o.x = f2bf(v.x); o.y = f2bf(v.y); o.z = f2bf(v.z); o.w = f2bf(v.w);
  ((ushort4*)out)[i] = o;
}

// ---------------- transpose fp32 (R x C) -> bf16 (C x R) ----------------
__global__ void transpose_cvt(const float* __restrict__ in, u16* __restrict__ out,
                              int R, int Ccols) {
  __shared__ float tile[32][33];
  int c0 = blockIdx.x * 32, r0 = blockIdx.y * 32;
  int tx = threadIdx.x & 31, ty = threadIdx.x >> 5;  // ty 0..7
#pragma unroll
  for (int i = 0; i < 32; i += 8)
    tile[ty + i][tx] = in[(size_t)(r0 + ty + i) * Ccols + c0 + tx];
  __syncthreads();
#pragma unroll
  for (int i = 0; i < 32; i += 8)
    out[(size_t)(c0 + ty + i) * R + r0 + tx] = f2bf(tile[tx][ty + i]);
}

// ---------------- transpose bf16 v (per b: T x 512 -> 512 x T) ----------------
__global__ void transpose_v16(const u16* __restrict__ in, u16* __restrict__ out) {
  __shared__ u16 tile[32][33];
  int b = blockIdx.z;
  int c0 = blockIdx.x * 32, t0 = blockIdx.y * 32;
  int tx = threadIdx.x & 31, ty = threadIdx.x >> 5;
  const u16* src = in + (size_t)b * T_ * (G_*HS_);
  u16* dst = out + (size_t)b * (G_*HS_) * T_;
#pragma unroll
  for (int i = 0; i < 32; i += 8)
    tile[ty + i][tx] = src[(size_t)(t0 + ty + i) * (G_*HS_) + c0 + tx];
  __syncthreads();
#pragma unroll
  for (int i = 0; i < 32; i += 8)
    dst[(size_t)(c0 + ty + i) * T_ + t0 + tx] = tile[tx][ty + i];
}

// ======== GEMM 256x256 tile, 8-phase pipelined (T2+T3+T4+T5) ========
// C[M][N] = A[M][K] * Bt[N][K]^T. 512 threads = 8 waves (2M x 4N), per-wave
// 128x64 output (acc[8][4]). BK=64 split into 2 K-halves of 32; LDS per
// matrix = 2 dbuf x 2 khalf x (256 rows x 32 k) bf16 = 64 KB (A) + 64 KB (B).
// LDS layout: pair-row P (128 B) holds rows {2P, 2P+1}; 16B chunks XOR-swizzled
// by (P&7). Swizzle applied on the GLOBAL source (linear global_load_lds dest)
// and on the ds_read address (both-sides, rule 21). Staging runs 6 half-tiles
// ahead of compute; vmcnt(8) counted waits (4 half-tiles in flight), tail
// drains 8 -> 4 -> 0. All barriers/waits are wave-uniform.
template<int N, int K, int OUTBF>
__global__ __launch_bounds__(512, 2)
void gemm256(const u16* __restrict__ A, const u16* __restrict__ Bt,
             u16* __restrict__ Cb, float* __restrict__ Cf) {
  __shared__ __align__(16) char lAs[65536];
  __shared__ __align__(16) char lBs[65536];
  const int tid  = threadIdx.x;
  const int lane = tid & 63;
  const int wave = tid >> 6;
  const int wm = wave >> 2, wn = wave & 3;
  const int fr = lane & 15, hi = lane >> 4;
  const int m0 = blockIdx.x * 256, n0 = blockIdx.y * 256;

  // fragment ds_read byte offsets within a 16KB half (row r, k-chunk hi)
  int aoff[8], boff[4];
#pragma unroll
  for (int mi = 0; mi < 8; ++mi) {
    int r = wm * 128 + mi * 16 + fr, P = r >> 1;
    aoff[mi] = P * 128 + (((((r & 1) << 2) | hi) ^ (P & 7)) << 4);
  }
#pragma unroll
  for (int ni = 0; ni < 4; ++ni) {
    int r = wn * 64 + ni * 16 + fr, P = r >> 1;
    boff[ni] = P * 128 + (((((r & 1) << 2) | hi) ^ (P & 7)) << 4);
  }

  // stage one 16KB half-tile: S = 4*ktile + j, j: 0=A-k0, 1=B-k0, 2=A-k1, 3=B-k1
  auto stage_half = [&](int S) {
    int kts = S >> 2, j = S & 3;
    int kk = j >> 1;
    const u16* src; int row0; char* base;
    if (j & 1) { src = Bt; row0 = n0; base = lBs; }
    else       { src = A;  row0 = m0; base = lAs; }
    base += ((kts & 1) * 2 + kk) * 16384;
    int kbase = kts * 64 + kk * 32;
#pragma unroll
    for (int i = 0; i < 2; ++i) {
      int L = i * 512 + tid;
      int P = L >> 3, c = L & 7;
      int l = c ^ (P & 7);          // logical chunk: (r&1)*4 + kchunk
      int r = 2 * P + (l >> 2);
      const u16* gs = src + (size_t)(row0 + r) * K + kbase + (l & 3) * 8;
      __builtin_amdgcn_global_load_lds(
          (__attribute__((address_space(1))) void*)gs,
          (__attribute__((address_space(3))) void*)(base + L * 16), 16, 0, 0);
    }
  };

  f32x4 acc[8][4] = {};

  // prologue: tile0 (4 halves) + tile1 (A-k0, B-k0)
#pragma unroll
  for (int S = 0; S < 6; ++S) stage_half(S);
  asm volatile("s_waitcnt vmcnt(8)" ::: "memory");
  __builtin_amdgcn_s_barrier();
  asm volatile("" ::: "memory");

  const int NK = K / 64;
  bf16x8 bcur[4];
  for (int kt = 0; kt < NK; ++kt) {
    const char* abase = lAs + (kt & 1) * 32768;
    const char* bbase = lBs + (kt & 1) * 32768;
    const bool s01 = kt < NK - 1;   // phases 0,1 stage tile kt+1 halves A-k1,B-k1
    const bool s23 = kt < NK - 2;   // phases 2,3 stage tile kt+2 halves A-k0,B-k0
#pragma unroll
    for (int p = 0; p < 4; ++p) {
      const int kk = p >> 1, wh = p & 1;
      const char* ab = abase + kk * 16384;
      const char* bb = bbase + kk * 16384;
      bf16x8 af[4];
      if (wh == 0) {
#pragma unroll
        for (int ni = 0; ni < 4; ++ni) bcur[ni] = *(const bf16x8*)(bb + boff[ni]);
      }
#pragma unroll
      for (int i = 0; i < 4; ++i) af[i] = *(const bf16x8*)(ab + aoff[wh * 4 + i]);
      if (p < 2 ? s01 : s23) stage_half(4 * kt + 6 + p);
      asm volatile("" ::: "memory");
      __builtin_amdgcn_s_barrier();
      __builtin_amdgcn_s_setprio(1);
#pragma unroll
      for (int i = 0; i < 4; ++i)
#pragma unroll
        for (int ni = 0; ni < 4; ++ni)
          acc[wh * 4 + i][ni] = __builtin_amdgcn_mfma_f32_16x16x32_bf16(
              af[i], bcur[ni], acc[wh * 4 + i][ni], 0, 0, 0);
      __builtin_amdgcn_s_setprio(0);
      if (p == 1) {
        if (kt == NK - 1) { asm volatile("s_waitcnt vmcnt(0)" ::: "memory"); }
        else              { asm volatile("s_waitcnt vmcnt(8)" ::: "memory"); }
      } else if (p == 3) {
        if (kt < NK - 2)       { asm volatile("s_waitcnt vmcnt(8)" ::: "memory"); }
        else if (kt == NK - 2) { asm volatile("s_waitcnt vmcnt(4)" ::: "memory"); }
      }
      __builtin_amdgcn_s_barrier();
      asm volatile("" ::: "memory");
    }
  }

  // epilogue
  const int orow = m0 + wm * 128 + hi * 4;
  const int ocol = n0 + wn * 64 + fr;
#pragma unroll
  for (int mi = 0; mi < 8; ++mi)
#pragma unroll
    for (int ni = 0; ni < 4; ++ni)
#pragma unroll
      for (int jj = 0; jj < 4; ++jj) {
        int r = orow + mi * 16 + jj, cc = ocol + ni * 16;
        if (OUTBF) Cb[(size_t)r * N + cc] = f2bf(acc[mi][ni][jj]);
        else       Cf[(size_t)r * N + cc] = acc[mi][ni][jj];
      }
}

// ---------------- conv(K=4) + SiLU helper ----------------
static __device__ __forceinline__ float conv_silu(const u16* __restrict__ qkv, int bt, int t,
                                                  int col, const float* __restrict__ w4) {
  float4 w = *(const float4*)w4;
  const u16* p = qkv + (size_t)bt * NQKV_ + col;
  float acc;
  if (t >= 3) {
    acc = w.x * bf2f(p[-3 * NQKV_]) + w.y * bf2f(p[-2 * NQKV_]) +
          w.z * bf2f(p[-1 * NQKV_]) + w.w * bf2f(p[0]);
  } else {
    acc = w.w * bf2f(p[0]);
    if (t >= 1) acc += w.z * bf2f(p[-1 * NQKV_]);
    if (t >= 2) acc += w.y * bf2f(p[-2 * NQKV_]);
  }
  return acc / (1.f + __expf(-acc));
}

// ---------------- q: conv + silu + rope (+fold SCALE) ----------------
__global__ void conv_rope_q(const u16* __restrict__ qkv, const float* __restrict__ w,
                            const float* __restrict__ cosT, const float* __restrict__ sinT,
                            u16* __restrict__ qout) {
  int part = blockIdx.x & 3;
  int bt = blockIdx.x >> 2;
  int t = bt & (T_ - 1);
  int pidx = part * 256 + threadIdx.x;
  int h = pidx >> 6, d = pidx & 63;
  int g = h >> 2, s = h & 3;
  int col = (g * 6 + s) * 128 + d;
  float a1 = conv_silu(qkv, bt, t, col,      w + (size_t)(h * 128 + d) * 4);
  float a2 = conv_silu(qkv, bt, t, col + 64, w + (size_t)(h * 128 + d + 64) * 4);
  float c = cosT[t * 64 + d], sn = sinT[t * 64 + d];
  u16* dst = qout + ((size_t)bt * NH_ + h) * HS_ + d;
  dst[0]  = f2bf((a1 * c - a2 * sn) * SCALE_);
  dst[64] = f2bf((a1 * sn + a2 * c) * SCALE_);
}

// ---------------- k: conv+silu+rope ; v: conv+silu ----------------
__global__ void conv_kv(const u16* __restrict__ qkv, const float* __restrict__ kw,
                        const float* __restrict__ vw, const float* __restrict__ cosT,
                        const float* __restrict__ sinT,
                        u16* __restrict__ kout, u16* __restrict__ vtmp) {
  int bt = blockIdx.x;
  int t = bt & (T_ - 1);
  int g = threadIdx.x >> 6, d = threadIdx.x & 63;
  if (blockIdx.y == 0) {
    int col = (g * 6 + 4) * 128 + d;
    float a1 = conv_silu(qkv, bt, t, col,      kw + (size_t)(g * 128 + d) * 4);
    float a2 = conv_silu(qkv, bt, t, col + 64, kw + (size_t)(g * 128 + d + 64) * 4);
    float c = cosT[t * 64 + d], sn = sinT[t * 64 + d];
    u16* dst = kout + ((size_t)bt * G_ + g) * HS_ + d;
    dst[0]  = f2bf(a1 * c - a2 * sn);
    dst[64] = f2bf(a1 * sn + a2 * c);
  } else {
    int col = (g * 6 + 5) * 128 + d;
    float a1 = conv_silu(qkv, bt, t, col,      vw + (size_t)(g * 128 + d) * 4);
    float a2 = conv_silu(qkv, bt, t, col + 64, vw + (size_t)(g * 128 + d + 64) * 4);
    u16* dst = vtmp + ((size_t)bt * G_ + g) * HS_ + d;
    dst[0]  = f2bf(a1);
    dst[64] = f2bf(a2);
  }
}

// ---------------- sliding-window GQA flash attention (v3) ----------------
__global__ __launch_bounds__(256, 2)
void attn_swin(const u16* __restrict__ qbf, const u16* __restrict__ kbf,
               const u16* __restrict__ vt, u16* __restrict__ ybf) {
  __shared__ __align__(16) char kls[2][16384];  // [64 s][256 B] swizzled
  __shared__ __align__(16) char vls[2][16384];  // [128 d][128 B] swizzled
  __shared__ __align__(16) char pls[4][2048];   // per-wave P [16 q][128 B] swizzled
  const int lane = threadIdx.x & 63;
  const int wave = threadIdx.x >> 6;
  const int btile = blockIdx.x & 31;
  const int h  = (blockIdx.x >> 5) & 15;
  const int b  = blockIdx.x >> 9;
  const int g  = h >> 2;
  const int t0b = btile << 6;
  const int t0w = t0b + wave * 16;
  const int fr = lane & 15;
  const int hi = lane >> 4;
  const int fko = hi * 8;
  const int qr = t0w + fr;
  char* pl = pls[wave];
  const int swz = (fr & 7) << 4;

  const int krow_l = (lane >> 4);
  const int kcb    = (lane & 15) * 16;
  const int vrow_l = (lane >> 3);
  const int vcb    = (lane & 7) * 16;

  bf16x8 qf[4];
  {
    const u16* qb = qbf + ((size_t)((b * T_ + t0w + fr) * NH_ + h)) * HS_ + fko;
#pragma unroll
    for (int kc = 0; kc < 4; ++kc) qf[kc] = ldg8(qb + kc * 32);
  }

  int sbeg = t0b - (WIN_ - 1); if (sbeg < 0) sbeg = 0; sbeg &= ~63;
  const int nt = (t0b + 64 - sbeg) >> 6;

  const char* kgbase = (const char*)kbf + (((size_t)(b * T_) * G_ + g) * HS_) * 2;
  const char* vgbase = (const char*)vt + ((size_t)(b * (G_*HS_) + g * HS_)) * T_ * 2;

  auto stage = [&](int bufi, int s0) {
    char* kb = kls[bufi]; char* vb = vls[bufi];
#pragma unroll
    for (int c = 0; c < 4; ++c) {
      int i = wave * 4 + c;
      {
        int row = i * 4 + krow_l;
        int scb = kcb ^ ((row & 7) << 4);
        const char* src = kgbase + (size_t)(s0 + row) * (G_*HS_*2) + scb;
        __builtin_amdgcn_global_load_lds(
            (__attribute__((address_space(1))) void*)src,
            (__attribute__((address_space(3))) void*)(kb + i * 1024), 16, 0, 0);
      }
      {
        int row = i * 8 + vrow_l;
        int scb = vcb ^ ((row & 7) << 4);
        const char* src = vgbase + (size_t)row * (T_*2) + (size_t)s0 * 2 + scb;
        __builtin_amdgcn_global_load_lds(
            (__attribute__((address_space(1))) void*)src,
            (__attribute__((address_space(3))) void*)(vb + i * 1024), 16, 0, 0);
      }
    }
  };

  f32x4 acc_o[8];
#pragma unroll
  for (int n = 0; n < 8; ++n) acc_o[n] = (f32x4){0.f, 0.f, 0.f, 0.f};
  float m_r = -1e30f, l_r = 0.f;

  stage(0, sbeg);
  __syncthreads();
  int cur = 0;

  for (int t = 0; t < nt; ++t) {
    int s0 = sbeg + (t << 6);
    if (t + 1 < nt) stage(cur ^ 1, s0 + 64);
    const char* kb = kls[cur];
    const char* vb = vls[cur];

    f32x4 st[4];
    __builtin_amdgcn_s_setprio(1);
#pragma unroll
    for (int c = 0; c < 4; ++c) {
      st[c] = (f32x4){0.f, 0.f, 0.f, 0.f};
      int row = c * 16 + fr;
#pragma unroll
      for (int kc = 0; kc < 4; ++kc) {
        bf16x8 kf = *(const bf16x8*)(kb + row * 256 + ((kc * 64 + hi * 16) ^ swz));
        st[c] = __builtin_amdgcn_mfma_f32_16x16x32_bf16(kf, qf[kc], st[c], 0, 0, 0);
      }
    }
    __builtin_amdgcn_s_setprio(0);

    float tmax = -1e30f;
#pragma unroll
    for (int c = 0; c < 4; ++c)
#pragma unroll
      for (int j = 0; j < 4; ++j) {
        int key = s0 + c * 16 + hi * 4 + j;
        int dlt = qr - key;
        float x = (dlt >= 0 && dlt < WIN_) ? st[c][j] : -1e30f;
        st[c][j] = x;
        tmax = fmaxf(tmax, x);
      }
    tmax = fmaxf(tmax, __shfl_xor(tmax, 16, 64));
    tmax = fmaxf(tmax, __shfl_xor(tmax, 32, 64));
    float mn  = fmaxf(m_r, tmax);
    float fac = __expf(m_r - mn);
    m_r = mn;

    float ps = 0.f;
#pragma unroll
    for (int c = 0; c < 4; ++c) {
      union { ushort4 u4; __bf16 hh[4]; } pk;
#pragma unroll
      for (int j = 0; j < 4; ++j) {
        float p = (st[c][j] > -1e29f) ? __expf(st[c][j] - mn) : 0.f;
        ps += p;
        pk.hh[j] = (__bf16)p;
      }
      *(ushort4*)(pl + fr * 128 + ((c * 32 + hi * 8) ^ swz)) = pk.u4;
    }
    ps += __shfl_xor(ps, 16, 64);
    ps += __shfl_xor(ps, 32, 64);
    l_r = l_r * fac + ps;

    float fq0 = __shfl(fac, hi * 4 + 0, 64);
    float fq1 = __shfl(fac, hi * 4 + 1, 64);
    float fq2 = __shfl(fac, hi * 4 + 2, 64);
    float fq3 = __shfl(fac, hi * 4 + 3, 64);
#pragma unroll
    for (int n = 0; n < 8; ++n) {
      acc_o[n][0] *= fq0; acc_o[n][1] *= fq1;
      acc_o[n][2] *= fq2; acc_o[n][3] *= fq3;
    }

#pragma unroll
    for (int ch = 0; ch < 2; ++ch) {
      bf16x8 pa = *(const bf16x8*)(pl + fr * 128 + ((ch * 64 + hi * 16) ^ swz));
      __builtin_amdgcn_s_setprio(1);
#pragma unroll
      for (int n = 0; n < 8; ++n) {
        int row = n * 16 + fr;
        bf16x8 vf = *(const bf16x8*)(vb + row * 128 + ((ch * 64 + hi * 16) ^ swz));
        acc_o[n] = __builtin_amdgcn_mfma_f32_16x16x32_bf16(pa, vf, acc_o[n], 0, 0, 0);
      }
      __builtin_amdgcn_s_setprio(0);
    }
    __syncthreads();
    cur ^= 1;
  }

  float inv = 1.f / l_r;
  float iq[4];
#pragma unroll
  for (int j = 0; j < 4; ++j) iq[j] = __shfl(inv, hi * 4 + j, 64);
#pragma unroll
  for (int n = 0; n < 8; ++n)
#pragma unroll
    for (int jj = 0; jj < 4; ++jj) {
      int t = t0w + hi * 4 + jj;
      ybf[((size_t)(b * T_ + t)) * (NH_*HS_) + h * HS_ + n * 16 + fr] = f2bf(acc_o[n][jj] * iq[jj]);
    }
}

extern "C" void kernel_launch(void* const* d_in, const int* in_sizes, int n_in,
                              void* d_out, int out_size, void* d_ws, size_t ws_size,
                              hipStream_t stream) {
  (void)in_sizes; (void)n_in; (void)out_size;
  const float* x     = (const float*)d_in[0];
  const float* Wqkv  = (const float*)d_in[1];
  const float* Wproj = (const float*)d_in[2];
  const float* qw    = (const float*)d_in[3];
  const float* kw    = (const float*)d_in[4];
  const float* vw    = (const float*)d_in[5];
  const float* cosT  = (const float*)d_in[6];
  const float* sinT  = (const float*)d_in[7];
  float* out = (float*)d_out;
  char* ws = (char*)d_ws;

  // workspace layout (bytes)
  u16* x_bf    = (u16*)(ws + 0);          // 4096*2048*2   = 16,777,216
  u16* wqkv_t  = (u16*)(ws + 16777216);   // 3072*2048*2   = 12,582,912
  u16* wproj_t = (u16*)(ws + 29360128);   // 2048*2048*2   =  8,388,608
  u16* qkv_bf  = (u16*)(ws + 37748736);   // 4096*3072*2   = 25,165,824
  u16* q_bf    = (u16*)(ws + 62914560);   // 2*2048*16*128*2 = 16,777,216
  u16* k_bf    = (u16*)(ws + 79691776);   // 2*2048*4*128*2  =  4,194,304
  u16* v_tmp   = (u16*)(ws + 83886080);   //                  4,194,304
  u16* v_t     = (u16*)(ws + 88080384);   //                  4,194,304
  u16* y_bf    = (u16*)(ws + 92274688);   // 4096*2048*2   = 16,777,216
  if (ws_size < (size_t)109051904) return;

  cvt_bf16<<<8192, 256, 0, stream>>>(x, x_bf);
  transpose_cvt<<<dim3(96, 64), 256, 0, stream>>>(Wqkv, wqkv_t, 2048, 3072);
  transpose_cvt<<<dim3(64, 64), 256, 0, stream>>>(Wproj, wproj_t, 2048, 2048);
  gemm256<3072, 2048, 1><<<dim3(16, 12), 512, 0, stream>>>(x_bf, wqkv_t, qkv_bf, nullptr);
  conv_rope_q<<<16384, 256, 0, stream>>>(qkv_bf, qw, cosT, sinT, q_bf);
  conv_kv<<<dim3(4096, 2), 256, 0, stream>>>(qkv_bf, kw, vw, cosT, sinT, k_bf, v_tmp);
  transpose_v16<<<dim3(16, 64, 2), 256, 0, stream>>>(v_tmp, v_t);
  attn_swin<<<1024, 256, 0, stream>>>(q_bf, k_bf, v_t, y_bf);
  gemm256<2048, 2048, 0><<<dim3(16, 8), 512, 0, stream>>>(y_bf, wproj_t, nullptr, out);
}

// Round 5
// 213.523 us; speedup vs baseline: 1.0767x; 1.0767x over previous
//
#include <hip/hip_runtime.h>
#include <math.h>
#include <stdint.h>

#define B_    2
#define T_    2048
#define C_    2048
#define NH_   16
#define G_    4
#define HS_   128
#define WIN_  512
#define NQKV_ 3072
#define M_    4096
#define SCALE_ 0.08838834764831845f

typedef __attribute__((ext_vector_type(8))) __bf16 bf16x8;
typedef __attribute__((ext_vector_type(4))) float f32x4;
typedef unsigned short u16;

static __device__ __forceinline__ u16 f2bf(float f) {
  union { float f; unsigned u; } v; v.f = f;
  unsigned r = v.u + 0x7fffu + ((v.u >> 16) & 1u);
  return (u16)(r >> 16);
}
static __device__ __forceinline__ float bf2f(u16 h) {
  union { unsigned u; float f; } v; v.u = ((unsigned)h) << 16; return v.f;
}
static __device__ __forceinline__ bf16x8 ldg8(const u16* p) {
  return *(const bf16x8*)(const void*)p;
}

// ---------------- x fp32 -> bf16 ----------------
__global__ void cvt_bf16(const float* __restrict__ in, u16* __restrict__ out) {
  int i = blockIdx.x * 256 + threadIdx.x;
  float4 v = ((const float4*)in)[i];
  ushort4 o;
  o.x = f2bf(v.x); o.y = f2bf(v.y); o.z = f2bf(v.z); o.w = f2bf(v.w);
  ((ushort4*)out)[i] = o;
}

// ---------------- transpose fp32 (R x C) -> bf16 (C x R) ----------------
__global__ void transpose_cvt(const float* __restrict__ in, u16* __restrict__ out,
                              int R, int Ccols) {
  __shared__ float tile[32][33];
  int c0 = blockIdx.x * 32, r0 = blockIdx.y * 32;
  int tx = threadIdx.x & 31, ty = threadIdx.x >> 5;  // ty 0..7
#pragma unroll
  for (int i = 0; i < 32; i += 8)
    tile[ty + i][tx] = in[(size_t)(r0 + ty + i) * Ccols + c0 + tx];
  __syncthreads();
#pragma unroll
  for (int i = 0; i < 32; i += 8)
    out[(size_t)(c0 + ty + i) * R + r0 + tx] = f2bf(tile[tx][ty + i]);
}

// ---------------- transpose bf16 v (per b: T x 512 -> 512 x T) ----------------
__global__ void transpose_v16(const u16* __restrict__ in, u16* __restrict__ out) {
  __shared__ u16 tile[32][33];
  int b = blockIdx.z;
  int c0 = blockIdx.x * 32, t0 = blockIdx.y * 32;
  int tx = threadIdx.x & 31, ty = threadIdx.x >> 5;
  const u16* src = in + (size_t)b * T_ * (G_*HS_);
  u16* dst = out + (size_t)b * (G_*HS_) * T_;
#pragma unroll
  for (int i = 0; i < 32; i += 8)
    tile[ty + i][tx] = src[(size_t)(t0 + ty + i) * (G_*HS_) + c0 + tx];
  __syncthreads();
#pragma unroll
  for (int i = 0; i < 32; i += 8)
    dst[(size_t)(c0 + ty + i) * T_ + t0 + tx] = tile[tx][ty + i];
}

// ---------------- GEMM: C[M][N] = A[M][K] * Bt[N][K]^T  (bf16 MFMA, m97-style) ----
// 128x128 tile, 4 waves, global_load_lds width-16. Measured round 3:
// qkv 65.2 us (790 TF, MfmaUtil 32%), proj ~43 us. 256^2 8-phase regressed
// (round 4: grid 192/128 blocks underfills 256 CUs) -> keep 128^2 here.
template<int N, int K, int OUTBF>
__global__ __launch_bounds__(256)
void gemm_bt(const u16* __restrict__ A, const u16* __restrict__ Bt,
             u16* __restrict__ Cb, float* __restrict__ Cf) {
  __shared__ u16 lA[128 * 32];
  __shared__ u16 lB[128 * 32];
  const int m0 = blockIdx.x * 128;
  const int n0 = blockIdx.y * 128;
  const int lane = threadIdx.x & 63;
  const int wave = threadIdx.x >> 6;
  const int wr = (wave >> 1) * 64, wc = (wave & 1) * 64;
  const int fr = lane & 15, fk = (lane >> 4) * 8;
  const int srow = lane >> 2;
  const int scol = (lane & 3) * 8;
  f32x4 acc[4][4] = {};
  for (int k0 = 0; k0 < K; k0 += 32) {
#pragma unroll
    for (int c = 0; c < 2; ++c) {
      int chunk = wave * 2 + c;
      int row = chunk * 16 + srow;
      __builtin_amdgcn_global_load_lds(
          (__attribute__((address_space(1))) void*)(A + (size_t)(m0 + row) * K + k0 + scol),
          (__attribute__((address_space(3))) void*)(lA + chunk * 512), 16, 0, 0);
      __builtin_amdgcn_global_load_lds(
          (__attribute__((address_space(1))) void*)(Bt + (size_t)(n0 + row) * K + k0 + scol),
          (__attribute__((address_space(3))) void*)(lB + chunk * 512), 16, 0, 0);
    }
    __syncthreads();
    bf16x8 af[4], bb[4];
#pragma unroll
    for (int i = 0; i < 4; ++i) {
      af[i] = ldg8(lA + (wr + i * 16 + fr) * 32 + fk);
      bb[i] = ldg8(lB + (wc + i * 16 + fr) * 32 + fk);
    }
#pragma unroll
    for (int i = 0; i < 4; ++i)
#pragma unroll
      for (int j = 0; j < 4; ++j)
        acc[i][j] = __builtin_amdgcn_mfma_f32_16x16x32_bf16(af[i], bb[j], acc[i][j], 0, 0, 0);
    __syncthreads();
  }
  const int orow = m0 + wr + (lane >> 4) * 4;
  const int ocol = n0 + wc + fr;
#pragma unroll
  for (int i = 0; i < 4; ++i)
#pragma unroll
    for (int j = 0; j < 4; ++j)
#pragma unroll
      for (int jj = 0; jj < 4; ++jj) {
        int r = orow + i * 16 + jj, cc = ocol + j * 16;
        if (OUTBF) Cb[(size_t)r * N + cc] = f2bf(acc[i][j][jj]);
        else       Cf[(size_t)r * N + cc] = acc[i][j][jj];
      }
}

// ---------------- q: conv+silu+rope, 8-wide vectorized ----------------
// thread -> 8 consecutive d in [0,64) for one (bt,h); loads 4 taps x 2 halves
// as bf16x8 (16B), weights as float4 (L1-resident), stores 2x16B.
__global__ void conv_rope_q(const u16* __restrict__ qkv, const float* __restrict__ w,
                            const float* __restrict__ cosT, const float* __restrict__ sinT,
                            u16* __restrict__ qout) {
  int tid = blockIdx.x * 256 + threadIdx.x;
  int d8 = (tid & 7) << 3;
  int h  = (tid >> 3) & 15;
  int bt = tid >> 7;
  int t  = bt & (T_ - 1);
  int g = h >> 2, s = h & 3;
  int col = (g * 6 + s) * 128 + d8;
  const u16* p = qkv + (size_t)bt * NQKV_ + col;

  bf16x8 lo[4], hi[4];
  const bf16x8 z8 = {};
#pragma unroll
  for (int k = 0; k < 4; ++k) {
    if (t + k >= 3) {
      long off = (long)(k - 3) * NQKV_;
      lo[k] = ldg8(p + off);
      hi[k] = ldg8(p + off + 64);
    } else { lo[k] = z8; hi[k] = z8; }
  }
  float4 c0 = *(const float4*)(cosT + t * 64 + d8);
  float4 c1 = *(const float4*)(cosT + t * 64 + d8 + 4);
  float4 s0 = *(const float4*)(sinT + t * 64 + d8);
  float4 s1 = *(const float4*)(sinT + t * 64 + d8 + 4);
  float cv[8] = {c0.x, c0.y, c0.z, c0.w, c1.x, c1.y, c1.z, c1.w};
  float sv[8] = {s0.x, s0.y, s0.z, s0.w, s1.x, s1.y, s1.z, s1.w};

  union { u16 a[8]; bf16x8 v; } olo, ohi;
#pragma unroll
  for (int j = 0; j < 8; ++j) {
    float4 wl = *(const float4*)(w + (size_t)(h * 128 + d8 + j) * 4);
    float4 wh = *(const float4*)(w + (size_t)(h * 128 + 64 + d8 + j) * 4);
    float a1 = wl.x * (float)lo[0][j] + wl.y * (float)lo[1][j] +
               wl.z * (float)lo[2][j] + wl.w * (float)lo[3][j];
    float a2 = wh.x * (float)hi[0][j] + wh.y * (float)hi[1][j] +
               wh.z * (float)hi[2][j] + wh.w * (float)hi[3][j];
    a1 = a1 / (1.f + __expf(-a1));
    a2 = a2 / (1.f + __expf(-a2));
    olo.a[j] = f2bf((a1 * cv[j] - a2 * sv[j]) * SCALE_);
    ohi.a[j] = f2bf((a1 * sv[j] + a2 * cv[j]) * SCALE_);
  }
  u16* dst = qout + ((size_t)bt * NH_ + h) * HS_ + d8;
  *(bf16x8*)(dst) = olo.v;
  *(bf16x8*)(dst + 64) = ohi.v;
}

// ---------------- k: conv+silu+rope ; v: conv+silu — 8-wide vectorized ------
__global__ void conv_kv(const u16* __restrict__ qkv, const float* __restrict__ kw,
                        const float* __restrict__ vw, const float* __restrict__ cosT,
                        const float* __restrict__ sinT,
                        u16* __restrict__ kout, u16* __restrict__ vtmp) {
  int tid = blockIdx.x * 256 + threadIdx.x;
  int idx = tid & 63;
  int bt  = tid >> 6;
  int t   = bt & (T_ - 1);
  int isv = idx >> 5;            // 0 = k, 1 = v
  int g   = (idx >> 3) & 3;
  int d8  = (idx & 7) << 3;
  int col = (g * 6 + 4 + isv) * 128 + d8;
  const float* w = isv ? vw : kw;
  const u16* p = qkv + (size_t)bt * NQKV_ + col;

  bf16x8 lo[4], hi[4];
  const bf16x8 z8 = {};
#pragma unroll
  for (int k = 0; k < 4; ++k) {
    if (t + k >= 3) {
      long off = (long)(k - 3) * NQKV_;
      lo[k] = ldg8(p + off);
      hi[k] = ldg8(p + off + 64);
    } else { lo[k] = z8; hi[k] = z8; }
  }

  float a1[8], a2[8];
#pragma unroll
  for (int j = 0; j < 8; ++j) {
    float4 wl = *(const float4*)(w + (size_t)(g * 128 + d8 + j) * 4);
    float4 wh = *(const float4*)(w + (size_t)(g * 128 + 64 + d8 + j) * 4);
    float x1 = wl.x * (float)lo[0][j] + wl.y * (float)lo[1][j] +
               wl.z * (float)lo[2][j] + wl.w * (float)lo[3][j];
    float x2 = wh.x * (float)hi[0][j] + wh.y * (float)hi[1][j] +
               wh.z * (float)hi[2][j] + wh.w * (float)hi[3][j];
    a1[j] = x1 / (1.f + __expf(-x1));
    a2[j] = x2 / (1.f + __expf(-x2));
  }

  union { u16 a[8]; bf16x8 v; } olo, ohi;
  if (isv == 0) {
#pragma unroll
    for (int j = 0; j < 8; ++j) {
      float c = cosT[t * 64 + d8 + j], sn = sinT[t * 64 + d8 + j];
      olo.a[j] = f2bf(a1[j] * c - a2[j] * sn);
      ohi.a[j] = f2bf(a1[j] * sn + a2[j] * c);
    }
    u16* dst = kout + ((size_t)bt * G_ + g) * HS_ + d8;
    *(bf16x8*)(dst) = olo.v;
    *(bf16x8*)(dst + 64) = ohi.v;
  } else {
#pragma unroll
    for (int j = 0; j < 8; ++j) {
      olo.a[j] = f2bf(a1[j]);
      ohi.a[j] = f2bf(a2[j]);
    }
    u16* dst = vtmp + ((size_t)bt * G_ + g) * HS_ + d8;
    *(bf16x8*)(dst) = olo.v;
    *(bf16x8*)(dst + 64) = ohi.v;
  }
}

// ---------------- sliding-window GQA flash attention (v3) ----------------
__global__ __launch_bounds__(256, 2)
void attn_swin(const u16* __restrict__ qbf, const u16* __restrict__ kbf,
               const u16* __restrict__ vt, u16* __restrict__ ybf) {
  __shared__ __align__(16) char kls[2][16384];  // [64 s][256 B] swizzled
  __shared__ __align__(16) char vls[2][16384];  // [128 d][128 B] swizzled
  __shared__ __align__(16) char pls[4][2048];   // per-wave P [16 q][128 B] swizzled
  const int lane = threadIdx.x & 63;
  const int wave = threadIdx.x >> 6;
  const int btile = blockIdx.x & 31;
  const int h  = (blockIdx.x >> 5) & 15;
  const int b  = blockIdx.x >> 9;
  const int g  = h >> 2;
  const int t0b = btile << 6;
  const int t0w = t0b + wave * 16;
  const int fr = lane & 15;
  const int hi = lane >> 4;
  const int fko = hi * 8;
  const int qr = t0w + fr;
  char* pl = pls[wave];
  const int swz = (fr & 7) << 4;

  const int krow_l = (lane >> 4);
  const int kcb    = (lane & 15) * 16;
  const int vrow_l = (lane >> 3);
  const int vcb    = (lane & 7) * 16;

  bf16x8 qf[4];
  {
    const u16* qb = qbf + ((size_t)((b * T_ + t0w + fr) * NH_ + h)) * HS_ + fko;
#pragma unroll
    for (int kc = 0; kc < 4; ++kc) qf[kc] = ldg8(qb + kc * 32);
  }

  int sbeg = t0b - (WIN_ - 1); if (sbeg < 0) sbeg = 0; sbeg &= ~63;
  const int nt = (t0b + 64 - sbeg) >> 6;

  const char* kgbase = (const char*)kbf + (((size_t)(b * T_) * G_ + g) * HS_) * 2;
  const char* vgbase = (const char*)vt + ((size_t)(b * (G_*HS_) + g * HS_)) * T_ * 2;

  auto stage = [&](int bufi, int s0) {
    char* kb = kls[bufi]; char* vb = vls[bufi];
#pragma unroll
    for (int c = 0; c < 4; ++c) {
      int i = wave * 4 + c;
      {
        int row = i * 4 + krow_l;
        int scb = kcb ^ ((row & 7) << 4);
        const char* src = kgbase + (size_t)(s0 + row) * (G_*HS_*2) + scb;
        __builtin_amdgcn_global_load_lds(
            (__attribute__((address_space(1))) void*)src,
            (__attribute__((address_space(3))) void*)(kb + i * 1024), 16, 0, 0);
      }
      {
        int row = i * 8 + vrow_l;
        int scb = vcb ^ ((row & 7) << 4);
        const char* src = vgbase + (size_t)row * (T_*2) + (size_t)s0 * 2 + scb;
        __builtin_amdgcn_global_load_lds(
            (__attribute__((address_space(1))) void*)src,
            (__attribute__((address_space(3))) void*)(vb + i * 1024), 16, 0, 0);
      }
    }
  };

  f32x4 acc_o[8];
#pragma unroll
  for (int n = 0; n < 8; ++n) acc_o[n] = (f32x4){0.f, 0.f, 0.f, 0.f};
  float m_r = -1e30f, l_r = 0.f;

  stage(0, sbeg);
  __syncthreads();
  int cur = 0;

  for (int t = 0; t < nt; ++t) {
    int s0 = sbeg + (t << 6);
    if (t + 1 < nt) stage(cur ^ 1, s0 + 64);
    const char* kb = kls[cur];
    const char* vb = vls[cur];

    f32x4 st[4];
    __builtin_amdgcn_s_setprio(1);
#pragma unroll
    for (int c = 0; c < 4; ++c) {
      st[c] = (f32x4){0.f, 0.f, 0.f, 0.f};
      int row = c * 16 + fr;
#pragma unroll
      for (int kc = 0; kc < 4; ++kc) {
        bf16x8 kf = *(const bf16x8*)(kb + row * 256 + ((kc * 64 + hi * 16) ^ swz));
        st[c] = __builtin_amdgcn_mfma_f32_16x16x32_bf16(kf, qf[kc], st[c], 0, 0, 0);
      }
    }
    __builtin_amdgcn_s_setprio(0);

    float tmax = -1e30f;
#pragma unroll
    for (int c = 0; c < 4; ++c)
#pragma unroll
      for (int j = 0; j < 4; ++j) {
        int key = s0 + c * 16 + hi * 4 + j;
        int dlt = qr - key;
        float x = (dlt >= 0 && dlt < WIN_) ? st[c][j] : -1e30f;
        st[c][j] = x;
        tmax = fmaxf(tmax, x);
      }
    tmax = fmaxf(tmax, __shfl_xor(tmax, 16, 64));
    tmax = fmaxf(tmax, __shfl_xor(tmax, 32, 64));
    float mn  = fmaxf(m_r, tmax);
    float fac = __expf(m_r - mn);
    m_r = mn;

    float ps = 0.f;
#pragma unroll
    for (int c = 0; c < 4; ++c) {
      union { ushort4 u4; __bf16 hh[4]; } pk;
#pragma unroll
      for (int j = 0; j < 4; ++j) {
        float p = (st[c][j] > -1e29f) ? __expf(st[c][j] - mn) : 0.f;
        ps += p;
        pk.hh[j] = (__bf16)p;
      }
      *(ushort4*)(pl + fr * 128 + ((c * 32 + hi * 8) ^ swz)) = pk.u4;
    }
    ps += __shfl_xor(ps, 16, 64);
    ps += __shfl_xor(ps, 32, 64);
    l_r = l_r * fac + ps;

    float fq0 = __shfl(fac, hi * 4 + 0, 64);
    float fq1 = __shfl(fac, hi * 4 + 1, 64);
    float fq2 = __shfl(fac, hi * 4 + 2, 64);
    float fq3 = __shfl(fac, hi * 4 + 3, 64);
#pragma unroll
    for (int n = 0; n < 8; ++n) {
      acc_o[n][0] *= fq0; acc_o[n][1] *= fq1;
      acc_o[n][2] *= fq2; acc_o[n][3] *= fq3;
    }

#pragma unroll
    for (int ch = 0; ch < 2; ++ch) {
      bf16x8 pa = *(const bf16x8*)(pl + fr * 128 + ((ch * 64 + hi * 16) ^ swz));
      __builtin_amdgcn_s_setprio(1);
#pragma unroll
      for (int n = 0; n < 8; ++n) {
        int row = n * 16 + fr;
        bf16x8 vf = *(const bf16x8*)(vb + row * 128 + ((ch * 64 + hi * 16) ^ swz));
        acc_o[n] = __builtin_amdgcn_mfma_f32_16x16x32_bf16(pa, vf, acc_o[n], 0, 0, 0);
      }
      __builtin_amdgcn_s_setprio(0);
    }
    __syncthreads();
    cur ^= 1;
  }

  float inv = 1.f / l_r;
  float iq[4];
#pragma unroll
  for (int j = 0; j < 4; ++j) iq[j] = __shfl(inv, hi * 4 + j, 64);
#pragma unroll
  for (int n = 0; n < 8; ++n)
#pragma unroll
    for (int jj = 0; jj < 4; ++jj) {
      int t = t0w + hi * 4 + jj;
      ybf[((size_t)(b * T_ + t)) * (NH_*HS_) + h * HS_ + n * 16 + fr] = f2bf(acc_o[n][jj] * iq[jj]);
    }
}

extern "C" void kernel_launch(void* const* d_in, const int* in_sizes, int n_in,
                              void* d_out, int out_size, void* d_ws, size_t ws_size,
                              hipStream_t stream) {
  (void)in_sizes; (void)n_in; (void)out_size;
  const float* x     = (const float*)d_in[0];
  const float* Wqkv  = (const float*)d_in[1];
  const float* Wproj = (const float*)d_in[2];
  const float* qw    = (const float*)d_in[3];
  const float* kw    = (const float*)d_in[4];
  const float* vw    = (const float*)d_in[5];
  const float* cosT  = (const float*)d_in[6];
  const float* sinT  = (const float*)d_in[7];
  float* out = (float*)d_out;
  char* ws = (char*)d_ws;

  // workspace layout (bytes)
  u16* x_bf    = (u16*)(ws + 0);          // 4096*2048*2   = 16,777,216
  u16* wqkv_t  = (u16*)(ws + 16777216);   // 3072*2048*2   = 12,582,912
  u16* wproj_t = (u16*)(ws + 29360128);   // 2048*2048*2   =  8,388,608
  u16* qkv_bf  = (u16*)(ws + 37748736);   // 4096*3072*2   = 25,165,824
  u16* q_bf    = (u16*)(ws + 62914560);   // 2*2048*16*128*2 = 16,777,216
  u16* k_bf    = (u16*)(ws + 79691776);   // 2*2048*4*128*2  =  4,194,304
  u16* v_tmp   = (u16*)(ws + 83886080);   //                  4,194,304
  u16* v_t     = (u16*)(ws + 88080384);   //                  4,194,304
  u16* y_bf    = (u16*)(ws + 92274688);   // 4096*2048*2   = 16,777,216
  if (ws_size < (size_t)109051904) return;

  cvt_bf16<<<8192, 256, 0, stream>>>(x, x_bf);
  transpose_cvt<<<dim3(96, 64), 256, 0, stream>>>(Wqkv, wqkv_t, 2048, 3072);
  transpose_cvt<<<dim3(64, 64), 256, 0, stream>>>(Wproj, wproj_t, 2048, 2048);
  gemm_bt<3072, 2048, 1><<<dim3(32, 24), 256, 0, stream>>>(x_bf, wqkv_t, qkv_bf, nullptr);
  conv_rope_q<<<2048, 256, 0, stream>>>(qkv_bf, qw, cosT, sinT, q_bf);
  conv_kv<<<1024, 256, 0, stream>>>(qkv_bf, kw, vw, cosT, sinT, k_bf, v_tmp);
  transpose_v16<<<dim3(16, 64, 2), 256, 0, stream>>>(v_tmp, v_t);
  attn_swin<<<1024, 256, 0, stream>>>(q_bf, k_bf, v_t, y_bf);
  gemm_bt<2048, 2048, 0><<<dim3(32, 16), 256, 0, stream>>>(y_bf, wproj_t, nullptr, out);
}

// Round 6
// 204.566 us; speedup vs baseline: 1.1239x; 1.0438x over previous
//
#include <hip/hip_runtime.h>
#include <math.h>
#include <stdint.h>

#define B_    2
#define T_    2048
#define C_    2048
#define NH_   16
#define G_    4
#define HS_   128
#define WIN_  512
#define NQKV_ 3072
#define M_    4096
#define SCALE_ 0.08838834764831845f

typedef __attribute__((ext_vector_type(8))) __bf16 bf16x8;
typedef __attribute__((ext_vector_type(4))) float f32x4;
typedef unsigned short u16;

static __device__ __forceinline__ u16 f2bf(float f) {
  union { float f; unsigned u; } v; v.f = f;
  unsigned r = v.u + 0x7fffu + ((v.u >> 16) & 1u);
  return (u16)(r >> 16);
}
static __device__ __forceinline__ float bf2f(u16 h) {
  union { unsigned u; float f; } v; v.u = ((unsigned)h) << 16; return v.f;
}
static __device__ __forceinline__ bf16x8 ldg8(const u16* p) {
  return *(const bf16x8*)(const void*)p;
}

// ---------------- fused prep: x->bf16  ||  Wqkv^T  ||  Wproj^T ----------------
__global__ void prep_all(const float* __restrict__ x, const float* __restrict__ Wqkv,
                         const float* __restrict__ Wproj,
                         u16* __restrict__ x_bf, u16* __restrict__ wqkv_t,
                         u16* __restrict__ wproj_t) {
  int blk = blockIdx.x;
  if (blk < 8192) {
    int i = blk * 256 + threadIdx.x;
    float4 v = ((const float4*)x)[i];
    ushort4 o;
    o.x = f2bf(v.x); o.y = f2bf(v.y); o.z = f2bf(v.z); o.w = f2bf(v.w);
    ((ushort4*)x_bf)[i] = o;
    return;
  }
  __shared__ float tile[32][33];
  const float* in; u16* out; int R, Ccols, bx, by;
  if (blk < 8192 + 6144) {
    int idx = blk - 8192;
    in = Wqkv; out = wqkv_t; R = 2048; Ccols = 3072;
    bx = idx % 96; by = idx / 96;
  } else {
    int idx = blk - 14336;
    in = Wproj; out = wproj_t; R = 2048; Ccols = 2048;
    bx = idx & 63; by = idx >> 6;
  }
  int c0 = bx * 32, r0 = by * 32;
  int tx = threadIdx.x & 31, ty = threadIdx.x >> 5;
#pragma unroll
  for (int i = 0; i < 32; i += 8)
    tile[ty + i][tx] = in[(size_t)(r0 + ty + i) * Ccols + c0 + tx];
  __syncthreads();
#pragma unroll
  for (int i = 0; i < 32; i += 8)
    out[(size_t)(c0 + ty + i) * R + r0 + tx] = f2bf(tile[tx][ty + i]);
}

// ---------------- transpose bf16 v (per b: T x 512 -> 512 x T) ----------------
__global__ void transpose_v16(const u16* __restrict__ in, u16* __restrict__ out) {
  __shared__ u16 tile[32][33];
  int b = blockIdx.z;
  int c0 = blockIdx.x * 32, t0 = blockIdx.y * 32;
  int tx = threadIdx.x & 31, ty = threadIdx.x >> 5;
  const u16* src = in + (size_t)b * T_ * (G_*HS_);
  u16* dst = out + (size_t)b * (G_*HS_) * T_;
#pragma unroll
  for (int i = 0; i < 32; i += 8)
    tile[ty + i][tx] = src[(size_t)(t0 + ty + i) * (G_*HS_) + c0 + tx];
  __syncthreads();
#pragma unroll
  for (int i = 0; i < 32; i += 8)
    dst[(size_t)(c0 + ty + i) * T_ + t0 + tx] = tile[tx][ty + i];
}

// ---------------- GEMM: C[M][N] = A[M][K] * Bt[N][K]^T  (bf16 MFMA, m97-style) ----
// 128x128 tile, 4 waves. Measured: qkv 65.2 us (790 TF), proj ~43 us.
// 256^2 8-phase regressed at these shapes (round 4, grid underfill) -> keep.
template<int N, int K, int OUTBF>
__global__ __launch_bounds__(256)
void gemm_bt(const u16* __restrict__ A, const u16* __restrict__ Bt,
             u16* __restrict__ Cb, float* __restrict__ Cf) {
  __shared__ u16 lA[128 * 32];
  __shared__ u16 lB[128 * 32];
  const int m0 = blockIdx.x * 128;
  const int n0 = blockIdx.y * 128;
  const int lane = threadIdx.x & 63;
  const int wave = threadIdx.x >> 6;
  const int wr = (wave >> 1) * 64, wc = (wave & 1) * 64;
  const int fr = lane & 15, fk = (lane >> 4) * 8;
  const int srow = lane >> 2;
  const int scol = (lane & 3) * 8;
  f32x4 acc[4][4] = {};
  for (int k0 = 0; k0 < K; k0 += 32) {
#pragma unroll
    for (int c = 0; c < 2; ++c) {
      int chunk = wave * 2 + c;
      int row = chunk * 16 + srow;
      __builtin_amdgcn_global_load_lds(
          (__attribute__((address_space(1))) void*)(A + (size_t)(m0 + row) * K + k0 + scol),
          (__attribute__((address_space(3))) void*)(lA + chunk * 512), 16, 0, 0);
      __builtin_amdgcn_global_load_lds(
          (__attribute__((address_space(1))) void*)(Bt + (size_t)(n0 + row) * K + k0 + scol),
          (__attribute__((address_space(3))) void*)(lB + chunk * 512), 16, 0, 0);
    }
    __syncthreads();
    bf16x8 af[4], bb[4];
#pragma unroll
    for (int i = 0; i < 4; ++i) {
      af[i] = ldg8(lA + (wr + i * 16 + fr) * 32 + fk);
      bb[i] = ldg8(lB + (wc + i * 16 + fr) * 32 + fk);
    }
#pragma unroll
    for (int i = 0; i < 4; ++i)
#pragma unroll
      for (int j = 0; j < 4; ++j)
        acc[i][j] = __builtin_amdgcn_mfma_f32_16x16x32_bf16(af[i], bb[j], acc[i][j], 0, 0, 0);
    __syncthreads();
  }
  const int orow = m0 + wr + (lane >> 4) * 4;
  const int ocol = n0 + wc + fr;
#pragma unroll
  for (int i = 0; i < 4; ++i)
#pragma unroll
    for (int j = 0; j < 4; ++j)
#pragma unroll
      for (int jj = 0; jj < 4; ++jj) {
        int r = orow + i * 16 + jj, cc = ocol + j * 16;
        if (OUTBF) Cb[(size_t)r * N + cc] = f2bf(acc[i][j][jj]);
        else       Cf[(size_t)r * N + cc] = acc[i][j][jj];
      }
}

// ---------------- fused conv: q (rope+scale) || k (rope) || v — 8-wide ------
__global__ void conv_all(const u16* __restrict__ qkv, const float* __restrict__ qw,
                         const float* __restrict__ kw, const float* __restrict__ vw,
                         const float* __restrict__ cosT, const float* __restrict__ sinT,
                         u16* __restrict__ qout, u16* __restrict__ kout,
                         u16* __restrict__ vtmp) {
  int blk = blockIdx.x;
  const bf16x8 z8 = {};
  if (blk < 2048) {
    // ---- q: conv+silu+rope (+fold SCALE) ----
    int tid = blk * 256 + threadIdx.x;
    int d8 = (tid & 7) << 3;
    int h  = (tid >> 3) & 15;
    int bt = tid >> 7;
    int t  = bt & (T_ - 1);
    int g = h >> 2, s = h & 3;
    int col = (g * 6 + s) * 128 + d8;
    const u16* p = qkv + (size_t)bt * NQKV_ + col;
    bf16x8 lo[4], hi[4];
#pragma unroll
    for (int k = 0; k < 4; ++k) {
      if (t + k >= 3) {
        long off = (long)(k - 3) * NQKV_;
        lo[k] = ldg8(p + off);
        hi[k] = ldg8(p + off + 64);
      } else { lo[k] = z8; hi[k] = z8; }
    }
    union { u16 a[8]; bf16x8 v; } olo, ohi;
#pragma unroll
    for (int j = 0; j < 8; ++j) {
      float4 wl = *(const float4*)(qw + (size_t)(h * 128 + d8 + j) * 4);
      float4 wh = *(const float4*)(qw + (size_t)(h * 128 + 64 + d8 + j) * 4);
      float a1 = wl.x * (float)lo[0][j] + wl.y * (float)lo[1][j] +
                 wl.z * (float)lo[2][j] + wl.w * (float)lo[3][j];
      float a2 = wh.x * (float)hi[0][j] + wh.y * (float)hi[1][j] +
                 wh.z * (float)hi[2][j] + wh.w * (float)hi[3][j];
      a1 = a1 / (1.f + __expf(-a1));
      a2 = a2 / (1.f + __expf(-a2));
      float c = cosT[t * 64 + d8 + j], sn = sinT[t * 64 + d8 + j];
      olo.a[j] = f2bf((a1 * c - a2 * sn) * SCALE_);
      ohi.a[j] = f2bf((a1 * sn + a2 * c) * SCALE_);
    }
    u16* dst = qout + ((size_t)bt * NH_ + h) * HS_ + d8;
    *(bf16x8*)(dst) = olo.v;
    *(bf16x8*)(dst + 64) = ohi.v;
  } else {
    // ---- k: conv+silu+rope ; v: conv+silu ----
    int tid = (blk - 2048) * 256 + threadIdx.x;
    int idx = tid & 63;
    int bt  = tid >> 6;
    int t   = bt & (T_ - 1);
    int isv = idx >> 5;
    int g   = (idx >> 3) & 3;
    int d8  = (idx & 7) << 3;
    int col = (g * 6 + 4 + isv) * 128 + d8;
    const float* w = isv ? vw : kw;
    const u16* p = qkv + (size_t)bt * NQKV_ + col;
    bf16x8 lo[4], hi[4];
#pragma unroll
    for (int k = 0; k < 4; ++k) {
      if (t + k >= 3) {
        long off = (long)(k - 3) * NQKV_;
        lo[k] = ldg8(p + off);
        hi[k] = ldg8(p + off + 64);
      } else { lo[k] = z8; hi[k] = z8; }
    }
    float a1[8], a2[8];
#pragma unroll
    for (int j = 0; j < 8; ++j) {
      float4 wl = *(const float4*)(w + (size_t)(g * 128 + d8 + j) * 4);
      float4 wh = *(const float4*)(w + (size_t)(g * 128 + 64 + d8 + j) * 4);
      float x1 = wl.x * (float)lo[0][j] + wl.y * (float)lo[1][j] +
                 wl.z * (float)lo[2][j] + wl.w * (float)lo[3][j];
      float x2 = wh.x * (float)hi[0][j] + wh.y * (float)hi[1][j] +
                 wh.z * (float)hi[2][j] + wh.w * (float)hi[3][j];
      a1[j] = x1 / (1.f + __expf(-x1));
      a2[j] = x2 / (1.f + __expf(-x2));
    }
    union { u16 a[8]; bf16x8 v; } olo, ohi;
    if (isv == 0) {
#pragma unroll
      for (int j = 0; j < 8; ++j) {
        float c = cosT[t * 64 + d8 + j], sn = sinT[t * 64 + d8 + j];
        olo.a[j] = f2bf(a1[j] * c - a2[j] * sn);
        ohi.a[j] = f2bf(a1[j] * sn + a2[j] * c);
      }
      u16* dst = kout + ((size_t)bt * G_ + g) * HS_ + d8;
      *(bf16x8*)(dst) = olo.v;
      *(bf16x8*)(dst + 64) = ohi.v;
    } else {
#pragma unroll
      for (int j = 0; j < 8; ++j) {
        olo.a[j] = f2bf(a1[j]);
        ohi.a[j] = f2bf(a2[j]);
      }
      u16* dst = vtmp + ((size_t)bt * G_ + g) * HS_ + d8;
      *(bf16x8*)(dst) = olo.v;
      *(bf16x8*)(dst + 64) = ohi.v;
    }
  }
}

// ---------------- sliding-window GQA flash attention (v4) ----------------
// block = 128 queries of one (b,h); 4 waves x 32q (two 16-row fragments).
// K/V 64-key tiles double-buffered in XOR-swizzled LDS (global_load_lds,
// swizzle on global source). kf/vf fragments shared across both Q-halves ->
// per-query staging, LDS reads, and barriers halve vs v3. T13 defer-max.
__global__ __launch_bounds__(256, 2)
void attn_swin(const u16* __restrict__ qbf, const u16* __restrict__ kbf,
               const u16* __restrict__ vt, u16* __restrict__ ybf) {
  __shared__ __align__(16) char kls[2][16384];  // [64 s][256 B] swizzled
  __shared__ __align__(16) char vls[2][16384];  // [128 d][128 B] swizzled
  __shared__ __align__(16) char pls[4][4096];   // per-wave P [32 q][128 B] swizzled
  const int lane = threadIdx.x & 63;
  const int wave = threadIdx.x >> 6;
  const int btile = blockIdx.x & 15;
  const int h  = (blockIdx.x >> 4) & 15;
  const int b  = blockIdx.x >> 8;
  const int g  = h >> 2;
  const int t0b = btile << 7;
  const int t0w = t0b + wave * 32;
  const int fr = lane & 15;
  const int hi = lane >> 4;
  const int fko = hi * 8;
  char* pl = pls[wave];
  const int swz = (fr & 7) << 4;

  const int krow_l = (lane >> 4);
  const int kcb    = (lane & 15) * 16;
  const int vrow_l = (lane >> 3);
  const int vcb    = (lane & 7) * 16;

  bf16x8 qf[2][4];
#pragma unroll
  for (int qh = 0; qh < 2; ++qh) {
    const u16* qb = qbf + ((size_t)((b * T_ + t0w + qh * 16 + fr) * NH_ + h)) * HS_ + fko;
#pragma unroll
    for (int kc = 0; kc < 4; ++kc) qf[qh][kc] = ldg8(qb + kc * 32);
  }

  int sbeg = t0b - (WIN_ - 1); if (sbeg < 0) sbeg = 0; sbeg &= ~63;
  const int nt = (t0b + 128 - sbeg) >> 6;

  const char* kgbase = (const char*)kbf + (((size_t)(b * T_) * G_ + g) * HS_) * 2;
  const char* vgbase = (const char*)vt + ((size_t)(b * (G_*HS_) + g * HS_)) * T_ * 2;

  auto stage = [&](int bufi, int s0) {
    char* kb = kls[bufi]; char* vb = vls[bufi];
#pragma unroll
    for (int c = 0; c < 4; ++c) {
      int i = wave * 4 + c;
      {
        int row = i * 4 + krow_l;
        int scb = kcb ^ ((row & 7) << 4);
        const char* src = kgbase + (size_t)(s0 + row) * (G_*HS_*2) + scb;
        __builtin_amdgcn_global_load_lds(
            (__attribute__((address_space(1))) void*)src,
            (__attribute__((address_space(3))) void*)(kb + i * 1024), 16, 0, 0);
      }
      {
        int row = i * 8 + vrow_l;
        int scb = vcb ^ ((row & 7) << 4);
        const char* src = vgbase + (size_t)row * (T_*2) + (size_t)s0 * 2 + scb;
        __builtin_amdgcn_global_load_lds(
            (__attribute__((address_space(1))) void*)src,
            (__attribute__((address_space(3))) void*)(vb + i * 1024), 16, 0, 0);
      }
    }
  };

  f32x4 acc_o[2][8];
#pragma unroll
  for (int qh = 0; qh < 2; ++qh)
#pragma unroll
    for (int n = 0; n < 8; ++n) acc_o[qh][n] = (f32x4){0.f, 0.f, 0.f, 0.f};
  float m_r[2] = {-1e30f, -1e30f}, l_r[2] = {0.f, 0.f};

  stage(0, sbeg);
  __syncthreads();
  int cur = 0;

  for (int t = 0; t < nt; ++t) {
    int s0 = sbeg + (t << 6);
    if (t + 1 < nt) stage(cur ^ 1, s0 + 64);
    const char* kb = kls[cur];
    const char* vb = vls[cur];

    // ---- QK^T (swapped): kf shared across both Q-halves ----
    f32x4 st[2][4];
#pragma unroll
    for (int qh = 0; qh < 2; ++qh)
#pragma unroll
      for (int c = 0; c < 4; ++c) st[qh][c] = (f32x4){0.f, 0.f, 0.f, 0.f};
    __builtin_amdgcn_s_setprio(1);
#pragma unroll
    for (int c = 0; c < 4; ++c) {
      int row = c * 16 + fr;
#pragma unroll
      for (int kc = 0; kc < 4; ++kc) {
        bf16x8 kf = *(const bf16x8*)(kb + row * 256 + ((kc * 64 + hi * 16) ^ swz));
        st[0][c] = __builtin_amdgcn_mfma_f32_16x16x32_bf16(kf, qf[0][kc], st[0][c], 0, 0, 0);
        st[1][c] = __builtin_amdgcn_mfma_f32_16x16x32_bf16(kf, qf[1][kc], st[1][c], 0, 0, 0);
      }
    }
    __builtin_amdgcn_s_setprio(0);

    // ---- per-qhalf: mask, max, exp, P write, defer-max rescale ----
#pragma unroll
    for (int qh = 0; qh < 2; ++qh) {
      int qr = t0w + qh * 16 + fr;
      float tmax = -1e30f;
#pragma unroll
      for (int c = 0; c < 4; ++c)
#pragma unroll
        for (int j = 0; j < 4; ++j) {
          int key = s0 + c * 16 + hi * 4 + j;
          int dlt = qr - key;
          float x = (dlt >= 0 && dlt < WIN_) ? st[qh][c][j] : -1e30f;
          st[qh][c][j] = x;
          tmax = fmaxf(tmax, x);
        }
      tmax = fmaxf(tmax, __shfl_xor(tmax, 16, 64));
      tmax = fmaxf(tmax, __shfl_xor(tmax, 32, 64));
      float fac = 1.f;
      bool need = !__all(tmax <= m_r[qh] + 8.f);   // T13 defer-max
      if (need) {
        float mn = fmaxf(m_r[qh], tmax);
        fac = __expf(m_r[qh] - mn);
        m_r[qh] = mn;
      }
      float ps = 0.f;
#pragma unroll
      for (int c = 0; c < 4; ++c) {
        union { ushort4 u4; __bf16 hh[4]; } pk;
#pragma unroll
        for (int j = 0; j < 4; ++j) {
          float p = (st[qh][c][j] > -1e29f) ? __expf(st[qh][c][j] - m_r[qh]) : 0.f;
          ps += p;
          pk.hh[j] = (__bf16)p;
        }
        *(ushort4*)(pl + (qh * 16 + fr) * 128 + ((c * 32 + hi * 8) ^ swz)) = pk.u4;
      }
      ps += __shfl_xor(ps, 16, 64);
      ps += __shfl_xor(ps, 32, 64);
      l_r[qh] = l_r[qh] * fac + ps;
      if (need) {
        float fq0 = __shfl(fac, hi * 4 + 0, 64);
        float fq1 = __shfl(fac, hi * 4 + 1, 64);
        float fq2 = __shfl(fac, hi * 4 + 2, 64);
        float fq3 = __shfl(fac, hi * 4 + 3, 64);
#pragma unroll
        for (int n = 0; n < 8; ++n) {
          acc_o[qh][n][0] *= fq0; acc_o[qh][n][1] *= fq1;
          acc_o[qh][n][2] *= fq2; acc_o[qh][n][3] *= fq3;
        }
      }
    }

    // ---- PV: vf shared across both Q-halves ----
#pragma unroll
    for (int ch = 0; ch < 2; ++ch) {
      bf16x8 pa0 = *(const bf16x8*)(pl + fr * 128 + ((ch * 64 + hi * 16) ^ swz));
      bf16x8 pa1 = *(const bf16x8*)(pl + (16 + fr) * 128 + ((ch * 64 + hi * 16) ^ swz));
      __builtin_amdgcn_s_setprio(1);
#pragma unroll
      for (int n = 0; n < 8; ++n) {
        int row = n * 16 + fr;
        bf16x8 vf = *(const bf16x8*)(vb + row * 128 + ((ch * 64 + hi * 16) ^ swz));
        acc_o[0][n] = __builtin_amdgcn_mfma_f32_16x16x32_bf16(pa0, vf, acc_o[0][n], 0, 0, 0);
        acc_o[1][n] = __builtin_amdgcn_mfma_f32_16x16x32_bf16(pa1, vf, acc_o[1][n], 0, 0, 0);
      }
      __builtin_amdgcn_s_setprio(0);
    }
    __syncthreads();
    cur ^= 1;
  }

  // ---- epilogue ----
#pragma unroll
  for (int qh = 0; qh < 2; ++qh) {
    float inv = 1.f / l_r[qh];
    float iq[4];
#pragma unroll
    for (int j = 0; j < 4; ++j) iq[j] = __shfl(inv, hi * 4 + j, 64);
#pragma unroll
    for (int n = 0; n < 8; ++n)
#pragma unroll
      for (int jj = 0; jj < 4; ++jj) {
        int t = t0w + qh * 16 + hi * 4 + jj;
        ybf[((size_t)(b * T_ + t)) * (NH_*HS_) + h * HS_ + n * 16 + fr] =
            f2bf(acc_o[qh][n][jj] * iq[jj]);
      }
  }
}

extern "C" void kernel_launch(void* const* d_in, const int* in_sizes, int n_in,
                              void* d_out, int out_size, void* d_ws, size_t ws_size,
                              hipStream_t stream) {
  (void)in_sizes; (void)n_in; (void)out_size;
  const float* x     = (const float*)d_in[0];
  const float* Wqkv  = (const float*)d_in[1];
  const float* Wproj = (const float*)d_in[2];
  const float* qw    = (const float*)d_in[3];
  const float* kw    = (const float*)d_in[4];
  const float* vw    = (const float*)d_in[5];
  const float* cosT  = (const float*)d_in[6];
  const float* sinT  = (const float*)d_in[7];
  float* out = (float*)d_out;
  char* ws = (char*)d_ws;

  // workspace layout (bytes)
  u16* x_bf    = (u16*)(ws + 0);          // 16,777,216
  u16* wqkv_t  = (u16*)(ws + 16777216);   // 12,582,912
  u16* wproj_t = (u16*)(ws + 29360128);   //  8,388,608
  u16* qkv_bf  = (u16*)(ws + 37748736);   // 25,165,824
  u16* q_bf    = (u16*)(ws + 62914560);   // 16,777,216
  u16* k_bf    = (u16*)(ws + 79691776);   //  4,194,304
  u16* v_tmp   = (u16*)(ws + 83886080);   //  4,194,304
  u16* v_t     = (u16*)(ws + 88080384);   //  4,194,304
  u16* y_bf    = (u16*)(ws + 92274688);   // 16,777,216
  if (ws_size < (size_t)109051904) return;

  prep_all<<<18432, 256, 0, stream>>>(x, Wqkv, Wproj, x_bf, wqkv_t, wproj_t);
  gemm_bt<3072, 2048, 1><<<dim3(32, 24), 256, 0, stream>>>(x_bf, wqkv_t, qkv_bf, nullptr);
  conv_all<<<3072, 256, 0, stream>>>(qkv_bf, qw, kw, vw, cosT, sinT, q_bf, k_bf, v_tmp);
  transpose_v16<<<dim3(16, 64, 2), 256, 0, stream>>>(v_tmp, v_t);
  attn_swin<<<512, 256, 0, stream>>>(q_bf, k_bf, v_t, y_bf);
  gemm_bt<2048, 2048, 0><<<dim3(32, 16), 256, 0, stream>>>(y_bf, wproj_t, nullptr, out);
}